// Round 7
// baseline (335.047 us; speedup 1.0000x reference)
//
#include <hip/hip_runtime.h>
#include <math.h>

// VGAE Encoder on MI355X — R7.
// R6 found k_agg2 FETCH=168MB ~= uncached gather volume: quarter tables were
// evicted by streams (sorted_src re-reads, per-edge dis[s] gathers, output).
// R7: (a) fold dis into the table: hml' = dis*hml, out = di*(sum hml'[s] +
// hml'[n]) + b  -> no per-edge dis gather at all; (b) non-temporal loads for
// all streams + nt stores for out so the 3.2MB quarter table stays L2-resident;
// (c) rows packed as int2.

#define CAPB  1280     // per-bucket total edge capacity (mean 1024, +8 sigma)
#define SCAP  224      // per-slice capacity (mean 128, +8.5 sigma)
#define NSL   8        // slices (XCDs)

typedef float f32x4 __attribute__((ext_vector_type(4)));

// ---------- pass A: bin edges into (slice, bucket) sub-regions ----------
__global__ void k_binfill(const int* __restrict__ src, const int* __restrict__ dst,
                          int* __restrict__ bcur, unsigned* __restrict__ pairs,
                          int E, int nbucket) {
    int sl = blockIdx.x & (NSL - 1);               // heuristic XCD id
    int* cur = bcur + sl * nbucket;
    unsigned* pp = pairs + (size_t)sl * nbucket * SCAP;
    int i = blockIdx.x * blockDim.x + threadIdx.x;
    int stride = gridDim.x * blockDim.x;
    for (; i < E; i += stride) {
        int d = __builtin_nontemporal_load(&dst[i]);
        unsigned s = (unsigned)__builtin_nontemporal_load(&src[i]);
        int b = d >> 6;
        int p = atomicAdd(&cur[b], 1);
        pp[b * SCAP + p] = ((unsigned)(d & 63) << 20) | s;   // src < 2^20
    }
}

// ---------- pass B: wave-per-bucket counting sort over 8 slices ----------
__global__ void k_bucket(const unsigned* __restrict__ pairs, const int* __restrict__ bcur,
                         int2* __restrict__ rows, float* __restrict__ dis,
                         int* __restrict__ sorted_src, int nbucket, int N) {
    __shared__ int hist[4][64];
    __shared__ int lbuf[4][CAPB];
    int w = threadIdx.x >> 6, lane = threadIdx.x & 63;
    int b = blockIdx.x * 4 + w;
    if (b >= nbucket) return;
    int ebase = b * CAPB;

    hist[w][lane] = 0;
    for (int sl = 0; sl < NSL; ++sl) {
        int size = bcur[sl * nbucket + b];
        const unsigned* pp = pairs + ((size_t)sl * nbucket + b) * SCAP;
        for (int e = lane; e < size; e += 64) {
            unsigned pr = __builtin_nontemporal_load(&pp[e]);
            atomicAdd(&hist[w][pr >> 20], 1);
        }
    }
    int v = hist[w][lane];
    int incl = v;
    for (int off = 1; off < 64; off <<= 1) {
        int a = __shfl_up(incl, off, 64);
        if (lane >= off) incl += a;
    }
    int excl = incl - v;
    int n = (b << 6) + lane;
    if (n < N) {
        rows[n] = make_int2(ebase + excl, ebase + incl);
        dis[n] = rsqrtf(1.0f + (float)v);
    }
    hist[w][lane] = excl;                       // local cursor
    int tot = __shfl(incl, 63, 64);             // bucket total
    for (int sl = 0; sl < NSL; ++sl) {
        int size = bcur[sl * nbucket + b];
        const unsigned* pp = pairs + ((size_t)sl * nbucket + b) * SCAP;
        for (int e = lane; e < size; e += 64) {
            unsigned pr = __builtin_nontemporal_load(&pp[e]);
            int slot = atomicAdd(&hist[w][pr >> 20], 1);
            lbuf[w][slot] = (int)(pr & 0xFFFFFu);
        }
    }
    for (int e = lane; e < tot; e += 64)        // coalesced drain
        sorted_src[ebase + e] = lbuf[w][e];
}

// ---------- fused gather + dense MLP: 32 lanes per node ----------
// ax = A_norm x; h = relu(ax W1 + b1); hml' = dis[n] * (h [W_mu|W_logstd])
__global__ void k_mlp(const float* __restrict__ x, const int2* __restrict__ rows,
                      const int* __restrict__ sorted_src, const float* __restrict__ dis,
                      const float* __restrict__ W1, const float* __restrict__ b1,
                      const float* __restrict__ W_mu, const float* __restrict__ W_logstd,
                      float* __restrict__ hml0, float* __restrict__ hml1,
                      float* __restrict__ hml2, float* __restrict__ hml3, int N) {
    __shared__ float W1s[128];
    __shared__ float b1s[64];
    __shared__ float Wcs[64 * 32];
    for (int t = threadIdx.x; t < 128; t += 256) W1s[t] = W1[t];
    for (int t = threadIdx.x; t < 64; t += 256) b1s[t] = b1[t];
    for (int t = threadIdx.x; t < 2048; t += 256) {
        int k = t >> 5, c = t & 31;
        Wcs[t] = (c < 16) ? W_mu[k * 16 + c] : W_logstd[k * 16 + (c - 16)];
    }
    __syncthreads();
    int node = blockIdx.x * 8 + (threadIdx.x >> 5);
    int c = threadIdx.x & 31;
    if (node >= N) return;
    const float2* x2 = (const float2*)x;
    float di = dis[node];
    int2 be = rows[node];
    float axx = 0.0f, axy = 0.0f;
    for (int e = be.x + c; e < be.y; e += 32) {
        int s = __builtin_nontemporal_load(&sorted_src[e]);
        float w = di * dis[s];
        float2 u = x2[s];
        axx = fmaf(w, u.x, axx);
        axy = fmaf(w, u.y, axy);
    }
#pragma unroll
    for (int off = 16; off; off >>= 1) {
        axx += __shfl_xor(axx, off, 32);
        axy += __shfl_xor(axy, off, 32);
    }
    float2 xv = x2[node];
    axx = fmaf(di * di, xv.x, axx);
    axy = fmaf(di * di, xv.y, axy);
    float h0 = fmaxf(fmaf(axx, W1s[c],      fmaf(axy, W1s[64 + c],  b1s[c])),      0.0f);
    float h1 = fmaxf(fmaf(axx, W1s[32 + c], fmaf(axy, W1s[96 + c],  b1s[32 + c])), 0.0f);
    float acc = 0.0f;
#pragma unroll
    for (int k = 0; k < 32; ++k) {
        float hk = __shfl(h0, k, 32);
        acc = fmaf(hk, Wcs[k * 32 + c], acc);
    }
#pragma unroll
    for (int k = 0; k < 32; ++k) {
        float hk = __shfl(h1, k, 32);
        acc = fmaf(hk, Wcs[(k + 32) * 32 + c], acc);
    }
    float* hq = (c < 8) ? hml0 : (c < 16) ? hml1 : (c < 24) ? hml2 : hml3;
    hq[(size_t)node * 8 + (c & 7)] = di * acc;    // hml' = dis * hml
}

// ---------- layer-2 aggregation: 4 quarters, XCD-partitioned, one launch ----------
// out[n] = di * (hml'[n] + sum_s hml'[s]) + bias  (dis folded into table)
__global__ void k_agg2(const float* __restrict__ hml0, const float* __restrict__ hml1,
                       const float* __restrict__ hml2, const float* __restrict__ hml3,
                       const int2* __restrict__ rows, const int* __restrict__ sorted_src,
                       const float* __restrict__ dis,
                       const float* __restrict__ b_mu, const float* __restrict__ b_logstd,
                       float* __restrict__ out, int N) {
    int b = blockIdx.x;
    int q = (b & 7) >> 1;                           // quarter -> XCDs {2q,2q+1}
    int sub = ((b >> 3) << 1) | (b & 1);
    int gid = sub * 256 + threadIdx.x;
    int node = gid >> 1, half = gid & 1;
    if (node >= N) return;
    const float4* h4 = (const float4*)(q == 0 ? hml0 : q == 1 ? hml1 : q == 2 ? hml2 : hml3);
    float di = dis[node];
    float4 acc = h4[(size_t)node * 2 + half];       // self-loop hml'[n]
    int2 be = rows[node];
    for (int k = be.x; k < be.y; ++k) {
        int s = __builtin_nontemporal_load(&sorted_src[k]);
        float4 u = h4[(size_t)s * 2 + half];
        acc.x += u.x; acc.y += u.y; acc.z += u.z; acc.w += u.w;
    }
    const float* bp = (q < 2 ? b_mu : b_logstd) + ((q & 1) << 3) + (half << 2);
    float4 bv = *(const float4*)bp;
    f32x4 res = { fmaf(di, acc.x, bv.x), fmaf(di, acc.y, bv.y),
                  fmaf(di, acc.z, bv.z), fmaf(di, acc.w, bv.w) };
    float* op = out + ((q < 2 ? (size_t)0 : (size_t)N) + node) * 16 + ((q & 1) << 3) + (half << 2);
    __builtin_nontemporal_store(res, (f32x4*)op);
}

extern "C" void kernel_launch(void* const* d_in, const int* in_sizes, int n_in,
                              void* d_out, int out_size, void* d_ws, size_t ws_size,
                              hipStream_t stream) {
    const float* x        = (const float*)d_in[0];
    const int*   eidx     = (const int*)d_in[1];
    const float* W1       = (const float*)d_in[2];
    const float* b1       = (const float*)d_in[3];
    const float* W_mu     = (const float*)d_in[4];
    const float* b_mu     = (const float*)d_in[5];
    const float* W_logstd = (const float*)d_in[6];
    const float* b_logstd = (const float*)d_in[7];
    float* out = (float*)d_out;

    const int N = in_sizes[0] / 2;            // 100000
    const int E = in_sizes[1] / 2;            // 1600000
    const int NBUCKET = (N + 63) >> 6;        // 1563

    const int* src = eidx;
    const int* dst = eidx + E;

    char* w = (char*)d_ws;
    auto alloc = [&](size_t bytes) -> void* {
        void* p = (void*)w;
        w += (bytes + 255) & ~(size_t)255;
        return p;
    };
    int*      bcur       = (int*)     alloc((size_t)NSL * NBUCKET * 4);
    unsigned* pairs      = (unsigned*)alloc((size_t)NSL * NBUCKET * SCAP * 4);
    int*      sorted_src = (int*)     alloc((size_t)NBUCKET * CAPB * 4);
    int2*     rows       = (int2*)    alloc((size_t)N * 8);
    float*    dis        = (float*)   alloc((size_t)N * 4);
    float*    hml0       = (float*)   alloc((size_t)N * 8 * 4);
    float*    hml1       = (float*)   alloc((size_t)N * 8 * 4);
    float*    hml2       = (float*)   alloc((size_t)N * 8 * 4);
    float*    hml3       = (float*)   alloc((size_t)N * 8 * 4);

    hipMemsetAsync(bcur, 0, (size_t)NSL * NBUCKET * 4, stream);

    k_binfill<<<2048, 256, 0, stream>>>(src, dst, bcur, pairs, E, NBUCKET);
    k_bucket <<<(NBUCKET + 3) / 4, 256, 0, stream>>>(pairs, bcur, rows, dis,
                                                     sorted_src, NBUCKET, N);
    k_mlp    <<<(N + 7) / 8, 256, 0, stream>>>(x, rows, sorted_src, dis,
                                               W1, b1, W_mu, W_logstd,
                                               hml0, hml1, hml2, hml3, N);
    int qblocks = (2 * N + 255) / 256;
    k_agg2   <<<((qblocks + 1) / 2) * 8, 256, 0, stream>>>(hml0, hml1, hml2, hml3,
                                                           rows, sorted_src, dis,
                                                           b_mu, b_logstd, out, N);
}